// Round 3
// baseline (329.525 us; speedup 1.0000x reference)
//
#include <hip/hip_runtime.h>
#include <stdint.h>

// Sizes fixed by the problem
#define BSZ 4
#define NSEQ 512
#define DMOD 1024
#define NH 16
#define HD 64

typedef __attribute__((ext_vector_type(8))) short bf16x8;
typedef __attribute__((ext_vector_type(4))) float f32x4;

__device__ __forceinline__ unsigned short f2bf(float f) {
    union { float f; uint32_t u; } v; v.f = f;
    uint32_t u = v.u;
    u += 0x7FFFu + ((u >> 16) & 1u);   // RNE
    return (unsigned short)(u >> 16);
}
__device__ __forceinline__ float bf2f(unsigned short b) {
    union { float f; uint32_t u; } v; v.u = ((uint32_t)b) << 16;
    return v.f;
}
__device__ __forceinline__ uint32_t pack2(float a, float b) {
    return (uint32_t)f2bf(a) | ((uint32_t)f2bf(b) << 16);
}

// ---------------- stage 1: conversions ----------------
__global__ void k_cvt(const float* __restrict__ src, unsigned short* __restrict__ dst, int n4) {
    int i = blockIdx.x * blockDim.x + threadIdx.x;
    if (i < n4) {
        float4 v = ((const float4*)src)[i];
        ushort4 o;
        o.x = f2bf(v.x); o.y = f2bf(v.y); o.z = f2bf(v.z); o.w = f2bf(v.w);
        ((ushort4*)dst)[i] = o;
    }
}

// transpose-convert weight: src[e][c] fp32 (1024x1024) -> dst[c][e] bf16; z selects wq/wk
__global__ void k_cvt_wt(const float* __restrict__ wq, const float* __restrict__ wk,
                         unsigned short* __restrict__ wqt, unsigned short* __restrict__ wkt) {
    const float* src = blockIdx.z ? wk : wq;
    unsigned short* dst = blockIdx.z ? wkt : wqt;
    __shared__ float t[32][33];
    int be = blockIdx.x * 32;   // e tile base
    int bc = blockIdx.y * 32;   // c tile base
    int tx = threadIdx.x & 31, ty = threadIdx.x >> 5;  // 32 x 8
    #pragma unroll
    for (int yy = 0; yy < 32; yy += 8)
        t[ty + yy][tx] = src[(size_t)(be + ty + yy) * DMOD + bc + tx];
    __syncthreads();
    #pragma unroll
    for (int yy = 0; yy < 32; yy += 8)
        dst[(size_t)(bc + ty + yy) * DMOD + be + tx] = f2bf(t[tx][ty + yy]);
}

// ---------------- stage 2: wv2t[h][e] = sum_d wv[e][h*64+d]*wo[h*64+d], bv2[h] ----------------
__global__ void k_wv2(const float* __restrict__ wv, const float* __restrict__ bv,
                      const float* __restrict__ wo,
                      float* __restrict__ wv2t, float* __restrict__ bv2) {
    int grp = threadIdx.x >> 6, l = threadIdx.x & 63;
    int e = blockIdx.x * 4 + grp;
    float out = 0.f;
    #pragma unroll
    for (int it = 0; it < 16; ++it) {      // column c = it*64 + l  ->  h = it, d = l
        float v = wv[(size_t)e * DMOD + it * 64 + l] * wo[it * 64 + l];
        #pragma unroll
        for (int off = 1; off < 64; off <<= 1) v += __shfl_xor(v, off, 64);
        if (l == it) out = v;
    }
    if (l < 16) wv2t[l * DMOD + e] = out;
    if (blockIdx.x == 0 && grp == 0) {
        float ob = 0.f;
        #pragma unroll
        for (int it = 0; it < 16; ++it) {
            float v = bv[it * 64 + l] * wo[it * 64 + l];
            #pragma unroll
            for (int off = 1; off < 64; off <<= 1) v += __shfl_xor(v, off, 64);
            if (l == it) ob = v;
        }
        if (l < 16) bv2[l] = ob;
    }
}

// ---------------- stage 2b: u[b][h][j] = x[b,j,:] @ wv2t[h,:] + bv2[h]  (fp32) ----------------
__global__ void k_u(const float* __restrict__ x, const float* __restrict__ wv2t,
                    const float* __restrict__ bv2, float* __restrict__ u) {
    int wave = blockIdx.x * 4 + (threadIdx.x >> 6);  // 2048 waves: one per (b,j)
    int l = threadIdx.x & 63;
    int b = wave >> 9, j = wave & 511;
    const float* xr = x + (size_t)(b * NSEQ + j) * DMOD;
    float p[16];
    #pragma unroll
    for (int h = 0; h < 16; ++h) p[h] = 0.f;
    for (int it = 0; it < 16; ++it) {
        int e = l + it * 64;
        float xv = xr[e];
        #pragma unroll
        for (int h = 0; h < 16; ++h) p[h] += xv * wv2t[h * DMOD + e];
    }
    #pragma unroll
    for (int h = 0; h < 16; ++h) {
        #pragma unroll
        for (int off = 1; off < 64; off <<= 1) p[h] += __shfl_xor(p[h], off, 64);
    }
    float out = 0.f;
    #pragma unroll
    for (int h = 0; h < 16; ++h) if (l == h) out = p[h] + bv2[h];
    if (l < 16) u[(b * 16 + l) * NSEQ + j] = out;
}

// ---------------- stage 3: projection GEMM (bf16 MFMA), Q and K fused via blockIdx.z ----------------
__global__ __launch_bounds__(256) void k_gemm(
        const unsigned short* __restrict__ X,     // 2048 x 1024 bf16 row-major
        const unsigned short* __restrict__ wqt, const unsigned short* __restrict__ wkt,
        const float* __restrict__ bq, const float* __restrict__ bk,
        unsigned short* __restrict__ qT, unsigned short* __restrict__ kT) {
    const unsigned short* Wt = blockIdx.z ? wkt : wqt;
    const float* bias = blockIdx.z ? bk : bq;
    unsigned short* outT = blockIdx.z ? kT : qT;
    int w = threadIdx.x >> 6, lane = threadIdx.x & 63;
    int quad = lane >> 4, col = lane & 15;
    int m0 = blockIdx.x * 64 + w * 16;
    int n0 = blockIdx.y * 64;
    f32x4 acc[4];
    #pragma unroll
    for (int nt = 0; nt < 4; ++nt) acc[nt] = (f32x4){0.f, 0.f, 0.f, 0.f};
    const unsigned short* arow = X + (size_t)(m0 + col) * DMOD + quad * 8;
    for (int k0 = 0; k0 < DMOD; k0 += 32) {
        bf16x8 a = *(const bf16x8*)(arow + k0);
        #pragma unroll
        for (int nt = 0; nt < 4; ++nt) {
            bf16x8 bf = *(const bf16x8*)(Wt + (size_t)(n0 + nt * 16 + col) * DMOD + k0 + quad * 8);
            acc[nt] = __builtin_amdgcn_mfma_f32_16x16x32_bf16(a, bf, acc[nt], 0, 0, 0);
        }
    }
    #pragma unroll
    for (int nt = 0; nt < 4; ++nt) {
        int n = n0 + nt * 16 + col;       // D-output col
        int h = n >> 6, d = n & 63;
        float bvv = bias[n];
        #pragma unroll
        for (int r = 0; r < 4; ++r) {
            int mg = m0 + quad * 4 + r;   // D-output row
            int b = mg >> 9, i = mg & 511;
            outT[(size_t)((b * 16 + h) * NSEQ + i) * HD + d] = f2bf(acc[nt][r] + bvv);
        }
    }
}

// ---------------- stage 4 (fused): logits+softmax+PV+force ----------------
// Grid (32 i-tiles, 8 h-groups, 4 b). Block = 8 waves = 2 h x 4 j-chunks.
// Per wave: 16 i x 128 j of e kept in 16 packed-bf16 VGPRs (two passes).
// s[i][j] accumulated in LDS atomics across waves; force from s and r, atomicAdd out.
#define SSTRIDE 516
__global__ __launch_bounds__(512) void k_attn(
        const unsigned short* __restrict__ qT, const unsigned short* __restrict__ kT,
        const float* __restrict__ bias, const int* __restrict__ mask,
        const float* __restrict__ u, const float* __restrict__ r,
        const float* __restrict__ bo, float* __restrict__ out) {
    __shared__ float s[16][SSTRIDE];
    __shared__ float sp_lds[2][16][4];
    int tid = threadIdx.x;
    int w = tid >> 6, lane = tid & 63;
    int quad = lane >> 4, col = lane & 15;
    int hl = w >> 2, jc = w & 3;
    int b = blockIdx.z, hg = blockIdx.y, i0 = blockIdx.x * 16;
    int h = hg * 2 + hl;
    int bh = b * 16 + h;

    // zero s tile
    #pragma unroll
    for (int t = 0; t < 17; ++t) {
        int idx = tid + t * 512;
        if (idx < 16 * SSTRIDE) (&s[0][0])[idx] = 0.f;
    }

    // q fragment (A operand): 16 i x 64 d
    const unsigned short* qbase = qT + ((size_t)(bh * NSEQ + i0 + col)) * HD + quad * 8;
    bf16x8 a0 = *(const bf16x8*)(qbase);
    bf16x8 a1 = *(const bf16x8*)(qbase + 32);

    uint32_t est[16];
    float sp[4] = {0.f, 0.f, 0.f, 0.f};

    const float* bias_b = bias + (size_t)bh * NSEQ * NSEQ;
    const int* mask_b = mask + (size_t)b * NSEQ * NSEQ;

    // pass 1: QK^T, bias, mask, exp (fixed shift), rowsum; stash e in regs
    #pragma unroll
    for (int jt = 0; jt < 8; ++jt) {
        int jtile = jc * 8 + ((jt + hl * 4) & 7);   // stagger 2 h-waves
        int j0 = jtile * 16;
        const unsigned short* kbase = kT + ((size_t)(bh * NSEQ + j0 + col)) * HD + quad * 8;
        bf16x8 b0 = *(const bf16x8*)(kbase);
        bf16x8 b1 = *(const bf16x8*)(kbase + 32);
        f32x4 acc = (f32x4){0.f, 0.f, 0.f, 0.f};
        acc = __builtin_amdgcn_mfma_f32_16x16x32_bf16(a0, b0, acc, 0, 0, 0);
        acc = __builtin_amdgcn_mfma_f32_16x16x32_bf16(a1, b1, acc, 0, 0, 0);
        int j = j0 + col;
        float e[4];
        #pragma unroll
        for (int rr = 0; rr < 4; ++rr) {
            int i = i0 + quad * 4 + rr;
            float lg = acc[rr] * 0.125f + bias_b[(size_t)i * NSEQ + j];
            float mk = (float)mask_b[(size_t)i * NSEQ + j];
            e[rr] = mk * __expf(lg - 30.f);
            sp[rr] += e[rr];
        }
        est[jt * 2]     = pack2(e[0], e[1]);
        est[jt * 2 + 1] = pack2(e[2], e[3]);
    }

    // reduce rowsums across 16 col lanes
    #pragma unroll
    for (int rr = 0; rr < 4; ++rr) {
        #pragma unroll
        for (int off = 1; off < 16; off <<= 1) sp[rr] += __shfl_xor(sp[rr], off, 64);
    }
    if (col == 0) {
        #pragma unroll
        for (int rr = 0; rr < 4; ++rr) sp_lds[hl][quad * 4 + rr][jc] = sp[rr];
    }
    __syncthreads();   // covers s-zero + sp_lds

    float siv[4];
    #pragma unroll
    for (int rr = 0; rr < 4; ++rr) {
        float4 p4 = *(const float4*)sp_lds[hl][quad * 4 + rr];
        float ssum = p4.x + p4.y + p4.z + p4.w;
        siv[rr] = (ssum > 0.f) ? 1.f / ssum : 0.f;
    }

    // pass 2: s[i][j] += e * sinv * u[h][j]
    const float* ub = u + (size_t)bh * NSEQ;
    #pragma unroll
    for (int jt = 0; jt < 8; ++jt) {
        int jtile = jc * 8 + ((jt + hl * 4) & 7);
        int j = jtile * 16 + col;
        float uv = ub[j];
        float e0 = bf2f((unsigned short)(est[jt * 2] & 0xffffu));
        float e1 = bf2f((unsigned short)(est[jt * 2] >> 16));
        float e2 = bf2f((unsigned short)(est[jt * 2 + 1] & 0xffffu));
        float e3 = bf2f((unsigned short)(est[jt * 2 + 1] >> 16));
        atomicAdd(&s[quad * 4 + 0][j], e0 * siv[0] * uv);
        atomicAdd(&s[quad * 4 + 1][j], e1 * siv[1] * uv);
        atomicAdd(&s[quad * 4 + 2][j], e2 * siv[2] * uv);
        atomicAdd(&s[quad * 4 + 3][j], e3 * siv[3] * uv);
    }
    __syncthreads();

    // force: wave w handles rows w and w+8; force[b,i,c] = sum_j r[b,c,i,j]*s[i][j]
    float bov = bo[0];
    #pragma unroll
    for (int rep = 0; rep < 2; ++rep) {
        int il = w + rep * 8;
        int i = i0 + il;
        float a0c = 0.f, a1c = 0.f, a2c = 0.f;
        #pragma unroll
        for (int t = 0; t < 8; ++t) {
            int j = lane + t * 64;
            float sv = s[il][j];
            a0c += r[((size_t)(b * 3 + 0) * NSEQ + i) * NSEQ + j] * sv;
            a1c += r[((size_t)(b * 3 + 1) * NSEQ + i) * NSEQ + j] * sv;
            a2c += r[((size_t)(b * 3 + 2) * NSEQ + i) * NSEQ + j] * sv;
        }
        #pragma unroll
        for (int off = 1; off < 64; off <<= 1) {
            a0c += __shfl_xor(a0c, off, 64);
            a1c += __shfl_xor(a1c, off, 64);
            a2c += __shfl_xor(a2c, off, 64);
        }
        if (lane == 0) {
            float addb = (hg == 0) ? bov : 0.f;
            atomicAdd(&out[(size_t)(b * NSEQ + i) * 3 + 0], a0c + addb);
            atomicAdd(&out[(size_t)(b * NSEQ + i) * 3 + 1], a1c + addb);
            atomicAdd(&out[(size_t)(b * NSEQ + i) * 3 + 2], a2c + addb);
        }
    }
}

extern "C" void kernel_launch(void* const* d_in, const int* in_sizes, int n_in,
                              void* d_out, int out_size, void* d_ws, size_t ws_size,
                              hipStream_t stream) {
    const float* x    = (const float*)d_in[0];
    const float* rr   = (const float*)d_in[1];
    const float* bias = (const float*)d_in[2];
    const int*   mask = (const int*)d_in[3];
    const float* wq   = (const float*)d_in[4];
    const float* bq   = (const float*)d_in[5];
    const float* wk   = (const float*)d_in[6];
    const float* bk   = (const float*)d_in[7];
    const float* wv   = (const float*)d_in[8];
    const float* bv   = (const float*)d_in[9];
    const float* wo   = (const float*)d_in[10];
    const float* bo   = (const float*)d_in[11];
    float* out = (float*)d_out;

    char* ws = (char*)d_ws;
    unsigned short* xb   = (unsigned short*)(ws + 0);          //  4 MiB
    unsigned short* wqt  = (unsigned short*)(ws + 4194304);    //  2 MiB
    unsigned short* wkt  = (unsigned short*)(ws + 6291456);    //  2 MiB
    float*          wv2t = (float*)(ws + 8388608);             //  64 KiB
    float*          bv2  = (float*)(ws + 8454144);             //  256 B
    float*          u    = (float*)(ws + 8454400);             //  128 KiB
    unsigned short* qT   = (unsigned short*)(ws + 8585472);    //  4 MiB
    unsigned short* kT   = (unsigned short*)(ws + 12779776);   //  4 MiB

    hipMemsetAsync(d_out, 0, (size_t)out_size * sizeof(float), stream);
    k_cvt<<<2048, 256, 0, stream>>>(x, xb, BSZ * NSEQ * DMOD / 4);
    k_cvt_wt<<<dim3(32, 32, 2), 256, 0, stream>>>(wq, wk, wqt, wkt);
    k_wv2<<<256, 256, 0, stream>>>(wv, bv, wo, wv2t, bv2);
    k_u<<<512, 256, 0, stream>>>(x, wv2t, bv2, u);
    k_gemm<<<dim3(32, 16, 2), 256, 0, stream>>>(xb, wqt, wkt, bq, bk, qT, kT);
    k_attn<<<dim3(32, 8, 4), 512, 0, stream>>>(qT, kT, bias, mask, u, rr, bo, out);
}

// Round 4
// 260.617 us; speedup vs baseline: 1.2644x; 1.2644x over previous
//
#include <hip/hip_runtime.h>
#include <hip/hip_fp16.h>
#include <stdint.h>

// Sizes fixed by the problem
#define BSZ 4
#define NSEQ 512
#define DMOD 1024
#define NH 16
#define HD 64

typedef __attribute__((ext_vector_type(8))) short bf16x8;
typedef __attribute__((ext_vector_type(4))) float f32x4;

__device__ __forceinline__ unsigned short f2bf(float f) {
    union { float f; uint32_t u; } v; v.f = f;
    uint32_t u = v.u;
    u += 0x7FFFu + ((u >> 16) & 1u);   // RNE
    return (unsigned short)(u >> 16);
}
__device__ __forceinline__ float bf2f(unsigned short b) {
    union { float f; uint32_t u; } v; v.u = ((uint32_t)b) << 16;
    return v.f;
}

// ============ A: prep — cvt x, transpose-cvt wq/wk, wv2/bv2, biasm (fp16, frag-permuted) ============
// grid 6400 blocks x 256 thr:
//   [0,2048)    : x fp32 -> bf16 (float4)
//   [2048,4096) : wq/wk transpose+cvt
//   [4096,4352) : wv2t[h][e] = sum_d wv[e][h*64+d]*wo[h*64+d]; bv2
//   [4352,6400) : biasm[tile(b,h,ti,tj)][lane][rr] fp16 = mask ? bias : -1e4
__global__ __launch_bounds__(256) void k_prep(
        const float* __restrict__ x, const float* __restrict__ wq, const float* __restrict__ wk,
        const float* __restrict__ wv, const float* __restrict__ bv, const float* __restrict__ wo,
        const float* __restrict__ bias, const int* __restrict__ mask,
        unsigned short* __restrict__ xb, unsigned short* __restrict__ wqt,
        unsigned short* __restrict__ wkt, float* __restrict__ wv2t, float* __restrict__ bv2,
        unsigned short* __restrict__ biasm) {
    __shared__ float t[32][33];
    int bx = blockIdx.x, tid = threadIdx.x;
    if (bx < 2048) {
        int i = bx * 256 + tid;
        float4 v = ((const float4*)x)[i];
        ushort4 o; o.x = f2bf(v.x); o.y = f2bf(v.y); o.z = f2bf(v.z); o.w = f2bf(v.w);
        ((ushort4*)xb)[i] = o;
    } else if (bx < 4096) {
        int g = bx - 2048; int z = g >> 10; g &= 1023;
        const float* src = z ? wk : wq;
        unsigned short* dst = z ? wkt : wqt;
        int be = (g & 31) * 32, bc = (g >> 5) * 32;
        int tx = tid & 31, ty = tid >> 5;
        #pragma unroll
        for (int yy = 0; yy < 32; yy += 8)
            t[ty + yy][tx] = src[(size_t)(be + ty + yy) * DMOD + bc + tx];
        __syncthreads();
        #pragma unroll
        for (int yy = 0; yy < 32; yy += 8)
            dst[(size_t)(bc + ty + yy) * DMOD + be + tx] = f2bf(t[tx][ty + yy]);
    } else if (bx < 4352) {
        int g = bx - 4096;
        int grp = tid >> 6, l = tid & 63;
        int e = g * 4 + grp;
        float out = 0.f;
        #pragma unroll
        for (int it = 0; it < 16; ++it) {
            float v = wv[(size_t)e * DMOD + it * 64 + l] * wo[it * 64 + l];
            #pragma unroll
            for (int off = 1; off < 64; off <<= 1) v += __shfl_xor(v, off, 64);
            if (l == it) out = v;
        }
        if (l < 16) wv2t[l * DMOD + e] = out;
        if (g == 0 && grp == 0) {
            float ob = 0.f;
            #pragma unroll
            for (int it = 0; it < 16; ++it) {
                float v = bv[it * 64 + l] * wo[it * 64 + l];
                #pragma unroll
                for (int off = 1; off < 64; off <<= 1) v += __shfl_xor(v, off, 64);
                if (l == it) ob = v;
            }
            if (l < 16) bv2[l] = ob;
        }
    } else {
        int g = bx - 4352;
        int ti = g & 31, h = (g >> 5) & 15, b = g >> 9;
        int l = tid & 63, pb = tid >> 6;
        int quad = l >> 4, col = l & 15;
        const float* brow = bias + (size_t)(b * 16 + h) * NSEQ * NSEQ;
        const int* mrow = mask + (size_t)b * NSEQ * NSEQ;
        #pragma unroll
        for (int pass = 0; pass < 8; ++pass) {
            int tj = pass * 4 + pb;
            int j = tj * 16 + col;
            ushort4 o;
            #pragma unroll
            for (int rr = 0; rr < 4; ++rr) {
                int i = ti * 16 + quad * 4 + rr;
                float bvv = brow[(size_t)i * NSEQ + j];
                int mk = mrow[(size_t)i * NSEQ + j];
                float val = mk ? bvv : -1.0e4f;
                ((unsigned short*)&o)[rr] = __half_as_ushort(__float2half(val));
            }
            size_t tile = ((size_t)((b * 16 + h) * 32 + ti)) * 32 + tj;
            *(ushort4*)(biasm + tile * 256 + l * 4) = o;
        }
    }
}

// ============ B: mid — u projection + Q/K MFMA GEMM (q pre-scaled by 1/8) ============
// grid 1536 blocks x 256 thr: [0,512)=k_u ; [512,1536)=gemm (g&31 m-tile, (g>>5)&15 n-tile, g>>9 z)
__global__ __launch_bounds__(256) void k_mid(
        const float* __restrict__ x, const float* __restrict__ wv2t, const float* __restrict__ bv2,
        const unsigned short* __restrict__ xb, const unsigned short* __restrict__ wqt,
        const unsigned short* __restrict__ wkt, const float* __restrict__ bq,
        const float* __restrict__ bk, float* __restrict__ u,
        unsigned short* __restrict__ qT, unsigned short* __restrict__ kT) {
    int bx = blockIdx.x, tid = threadIdx.x;
    if (bx < 512) {
        int wave = bx * 4 + (tid >> 6);
        int l = tid & 63;
        int b = wave >> 9, j = wave & 511;
        const float* xr = x + (size_t)(b * NSEQ + j) * DMOD;
        float p[16];
        #pragma unroll
        for (int h = 0; h < 16; ++h) p[h] = 0.f;
        for (int it = 0; it < 16; ++it) {
            int e = l + it * 64;
            float xv = xr[e];
            #pragma unroll
            for (int h = 0; h < 16; ++h) p[h] += xv * wv2t[h * DMOD + e];
        }
        #pragma unroll
        for (int h = 0; h < 16; ++h) {
            #pragma unroll
            for (int off = 1; off < 64; off <<= 1) p[h] += __shfl_xor(p[h], off, 64);
        }
        float out = 0.f;
        #pragma unroll
        for (int h = 0; h < 16; ++h) if (l == h) out = p[h] + bv2[h];
        if (l < 16) u[(b * 16 + l) * NSEQ + j] = out;
    } else {
        int g = bx - 512;
        int z = g >> 9;
        const unsigned short* Wt = z ? wkt : wqt;
        const float* bias = z ? bk : bq;
        unsigned short* outT = z ? kT : qT;
        float scale = z ? 1.f : 0.125f;   // fold /sqrt(HD)=1/8 into q
        int w = tid >> 6, lane = tid & 63;
        int quad = lane >> 4, col = lane & 15;
        int m0 = (g & 31) * 64 + w * 16;
        int n0 = ((g >> 5) & 15) * 64;
        f32x4 acc[4];
        #pragma unroll
        for (int nt = 0; nt < 4; ++nt) acc[nt] = (f32x4){0.f, 0.f, 0.f, 0.f};
        const unsigned short* arow = xb + (size_t)(m0 + col) * DMOD + quad * 8;
        for (int k0 = 0; k0 < DMOD; k0 += 32) {
            bf16x8 a = *(const bf16x8*)(arow + k0);
            #pragma unroll
            for (int nt = 0; nt < 4; ++nt) {
                bf16x8 bf = *(const bf16x8*)(Wt + (size_t)(n0 + nt * 16 + col) * DMOD + k0 + quad * 8);
                acc[nt] = __builtin_amdgcn_mfma_f32_16x16x32_bf16(a, bf, acc[nt], 0, 0, 0);
            }
        }
        #pragma unroll
        for (int nt = 0; nt < 4; ++nt) {
            int n = n0 + nt * 16 + col;
            int h = n >> 6, d = n & 63;
            float bvv = bias[n];
            #pragma unroll
            for (int r = 0; r < 4; ++r) {
                int mg = m0 + quad * 4 + r;
                int b = mg >> 9, i = mg & 511;
                outT[(size_t)((b * 16 + h) * NSEQ + i) * HD + d] = f2bf((acc[nt][r] + bvv) * scale);
            }
        }
    }
}

// ============ C: logits+exp (fixed-shift-free), eW via LDS transpose ============
// grid 4096: it=bx&7, jc=(bx>>3)&7, h=(bx>>6)&15, b=bx>>10. Block 4 waves; wave: 16 i x 64 j.
__global__ __launch_bounds__(256) void k_logits(
        const unsigned short* __restrict__ qT, const unsigned short* __restrict__ kT,
        const unsigned short* __restrict__ biasm,
        unsigned short* __restrict__ eW, float* __restrict__ spart) {
    __shared__ unsigned short elds[4][16][66];
    int tid = threadIdx.x, w = tid >> 6, lane = tid & 63;
    int quad = lane >> 4, col = lane & 15;
    int bx = blockIdx.x;
    int it = bx & 7, jc = (bx >> 3) & 7, h = (bx >> 6) & 15, b = bx >> 10;
    int bh = b * 16 + h;
    int i0 = it * 64 + w * 16;
    int j0 = jc * 64;

    const unsigned short* qbase = qT + ((size_t)(bh * NSEQ + i0 + col)) * HD + quad * 8;
    bf16x8 a0 = *(const bf16x8*)qbase;
    bf16x8 a1 = *(const bf16x8*)(qbase + 32);

    // issue all loads up front: 8 kT frags + 4 biasm dwords
    bf16x8 kf0[4], kf1[4];
    uint2 bm[4];
    #pragma unroll
    for (int jt = 0; jt < 4; ++jt) {
        const unsigned short* kbase = kT + ((size_t)(bh * NSEQ + j0 + jt * 16 + col)) * HD + quad * 8;
        kf0[jt] = *(const bf16x8*)kbase;
        kf1[jt] = *(const bf16x8*)(kbase + 32);
        size_t tile = ((size_t)(bh * 32 + it * 4 + w)) * 32 + (jc * 4 + jt);
        bm[jt] = *(const uint2*)(biasm + tile * 256 + lane * 4);
    }

    float sp[4] = {0.f, 0.f, 0.f, 0.f};
    #pragma unroll
    for (int jt = 0; jt < 4; ++jt) {
        f32x4 acc = (f32x4){0.f, 0.f, 0.f, 0.f};
        acc = __builtin_amdgcn_mfma_f32_16x16x32_bf16(a0, kf0[jt], acc, 0, 0, 0);
        acc = __builtin_amdgcn_mfma_f32_16x16x32_bf16(a1, kf1[jt], acc, 0, 0, 0);
        unsigned short hb[4];
        hb[0] = (unsigned short)(bm[jt].x & 0xffffu);
        hb[1] = (unsigned short)(bm[jt].x >> 16);
        hb[2] = (unsigned short)(bm[jt].y & 0xffffu);
        hb[3] = (unsigned short)(bm[jt].y >> 16);
        #pragma unroll
        for (int rr = 0; rr < 4; ++rr) {
            float lg = acc[rr] + __half2float(__ushort_as_half(hb[rr]));
            float ev = __expf(lg);
            sp[rr] += ev;
            elds[w][quad * 4 + rr][jt * 16 + col] = f2bf(ev);
        }
    }
    // rowsum over the 16 col-lanes
    #pragma unroll
    for (int rr = 0; rr < 4; ++rr) {
        #pragma unroll
        for (int off = 1; off < 16; off <<= 1) sp[rr] += __shfl_xor(sp[rr], off, 64);
    }
    if (col == 0) {
        #pragma unroll
        for (int rr = 0; rr < 4; ++rr)
            spart[((size_t)(bh * NSEQ) + i0 + quad * 4 + rr) * 8 + jc] = sp[rr];
    }
    __syncthreads();
    // write eW rows: 128B contiguous segments, 2 rows per instr
    #pragma unroll
    for (int k2 = 0; k2 < 8; ++k2) {
        int row = (lane >> 5) + k2 * 2;
        int jseg = (lane & 31) * 2;
        uint32_t val = *(const uint32_t*)&elds[w][row][jseg];
        int i = i0 + row;
        *(uint32_t*)(eW + (((size_t)(b * NSEQ + i) * NH + h) * NSEQ) + j0 + jseg) = val;
    }
}

// ============ E: sinv + combine ============
// grid 1024: ip=bx&255 (2 rows), b=bx>>8. eW [b][i][h][j] staged in LDS.
__global__ __launch_bounds__(256) void k_combine(
        const unsigned short* __restrict__ eW, const float* __restrict__ spart,
        const float* __restrict__ u, const float* __restrict__ r,
        const float* __restrict__ bo, float* __restrict__ out) {
    __shared__ __align__(16) unsigned short elds[2][NH][NSEQ];   // 32 KB
    __shared__ float su[2][16];
    __shared__ float red[2][2][3];
    int tid = threadIdx.x, bx = blockIdx.x;
    int ip = bx & 255, b = bx >> 8;
    int i0 = ip * 2;
    const unsigned short* esrc = eW + (size_t)(b * NSEQ + i0) * NH * NSEQ;
    #pragma unroll
    for (int t = 0; t < 8; ++t)
        ((int4*)&elds[0][0][0])[tid + t * 256] = ((const int4*)esrc)[tid + t * 256];
    {   // sinv: 128 threads per row; 16 h x 8 jc partials
        int il = tid >> 7, hq = (tid >> 3) & 15, jcq = tid & 7;
        float v = spart[((size_t)((b * 16 + hq) * NSEQ) + i0 + il) * 8 + jcq];
        v += __shfl_xor(v, 1, 64); v += __shfl_xor(v, 2, 64); v += __shfl_xor(v, 4, 64);
        if (jcq == 0) su[il][hq] = (v > 0.f) ? 1.f / v : 0.f;
    }
    __syncthreads();
    int il = tid >> 7, jj = tid & 127, j = jj * 4;
    int i = i0 + il;
    float s0 = 0.f, s1 = 0.f, s2 = 0.f, s3 = 0.f;
    #pragma unroll
    for (int h = 0; h < 16; ++h) {
        float wgt = su[il][h];
        float4 uv = *(const float4*)(u + (size_t)(b * 16 + h) * NSEQ + j);
        uint2 ep = *(const uint2*)&elds[il][h][j];
        s0 += bf2f((unsigned short)(ep.x & 0xffffu)) * wgt * uv.x;
        s1 += bf2f((unsigned short)(ep.x >> 16)) * wgt * uv.y;
        s2 += bf2f((unsigned short)(ep.y & 0xffffu)) * wgt * uv.z;
        s3 += bf2f((unsigned short)(ep.y >> 16)) * wgt * uv.w;
    }
    float acc[3];
    #pragma unroll
    for (int c = 0; c < 3; ++c) {
        float4 rv = *(const float4*)(r + ((size_t)(b * 3 + c) * NSEQ + i) * NSEQ + j);
        acc[c] = rv.x * s0 + rv.y * s1 + rv.z * s2 + rv.w * s3;
    }
    #pragma unroll
    for (int c = 0; c < 3; ++c) {
        #pragma unroll
        for (int off = 1; off < 64; off <<= 1) acc[c] += __shfl_xor(acc[c], off, 64);
    }
    int wv = tid >> 6, lane = tid & 63;
    if (lane == 0) {
        red[wv >> 1][wv & 1][0] = acc[0];
        red[wv >> 1][wv & 1][1] = acc[1];
        red[wv >> 1][wv & 1][2] = acc[2];
    }
    __syncthreads();
    if (tid < 6) {
        int ilo = tid / 3, c = tid % 3;
        out[(size_t)(b * NSEQ + i0 + ilo) * 3 + c] = red[ilo][0][c] + red[ilo][1][c] + bo[0];
    }
}

extern "C" void kernel_launch(void* const* d_in, const int* in_sizes, int n_in,
                              void* d_out, int out_size, void* d_ws, size_t ws_size,
                              hipStream_t stream) {
    const float* x    = (const float*)d_in[0];
    const float* rr   = (const float*)d_in[1];
    const float* bias = (const float*)d_in[2];
    const int*   mask = (const int*)d_in[3];
    const float* wq   = (const float*)d_in[4];
    const float* bq   = (const float*)d_in[5];
    const float* wk   = (const float*)d_in[6];
    const float* bk   = (const float*)d_in[7];
    const float* wv   = (const float*)d_in[8];
    const float* bv   = (const float*)d_in[9];
    const float* wo   = (const float*)d_in[10];
    const float* bo   = (const float*)d_in[11];
    float* out = (float*)d_out;

    char* ws = (char*)d_ws;
    unsigned short* xb   = (unsigned short*)(ws + 0);          //  4 MiB
    unsigned short* wqt  = (unsigned short*)(ws + 4194304);    //  2 MiB
    unsigned short* wkt  = (unsigned short*)(ws + 6291456);    //  2 MiB
    float*          wv2t = (float*)(ws + 8388608);             //  64 KiB
    float*          bv2  = (float*)(ws + 8454144);             //  256 B
    float*          u    = (float*)(ws + 8454400);             //  128 KiB
    unsigned short* qT   = (unsigned short*)(ws + 8585472);    //  4 MiB
    unsigned short* kT   = (unsigned short*)(ws + 12779776);   //  4 MiB
    unsigned short* bm   = (unsigned short*)(ws + 16974080);   //  32 MiB fp16, frag-permuted
    unsigned short* eW   = (unsigned short*)(ws + 50528512);   //  32 MiB bf16 [b][i][h][j]
    float*          spart= (float*)(ws + 84082944);            //  1 MiB
    // total ~85.1 MB

    k_prep<<<6400, 256, 0, stream>>>(x, wq, wk, wv, bv, wo, bias, mask,
                                     xb, wqt, wkt, wv2t, bv2, bm);
    k_mid<<<1536, 256, 0, stream>>>(x, wv2t, bv2, xb, wqt, wkt, bq, bk, u, qT, kT);
    k_logits<<<4096, 256, 0, stream>>>(qT, kT, bm, eW, spart);
    k_combine<<<1024, 256, 0, stream>>>(eW, spart, u, rr, bo, out);
}

// Round 5
// 208.148 us; speedup vs baseline: 1.5831x; 1.2521x over previous
//
#include <hip/hip_runtime.h>
#include <hip/hip_fp16.h>
#include <stdint.h>

// Sizes fixed by the problem
#define BSZ 4
#define NSEQ 512
#define DMOD 1024
#define NH 16
#define HD 64

typedef __attribute__((ext_vector_type(8))) short bf16x8;
typedef __attribute__((ext_vector_type(4))) float f32x4;

__device__ __forceinline__ unsigned short f2bf(float f) {
    union { float f; uint32_t u; } v; v.f = f;
    uint32_t u = v.u;
    u += 0x7FFFu + ((u >> 16) & 1u);   // RNE
    return (unsigned short)(u >> 16);
}
__device__ __forceinline__ float bf2f(unsigned short b) {
    union { float f; uint32_t u; } v; v.u = ((uint32_t)b) << 16;
    return v.f;
}

__device__ __forceinline__ void gload_lds16(const unsigned short* g, unsigned short* l) {
    __builtin_amdgcn_global_load_lds(
        (const __attribute__((address_space(1))) void*)g,
        (__attribute__((address_space(3))) void*)l, 16, 0, 0);
}

// ============ A: prep — cvt x, transpose-cvt wq/wk, wv2/bv2, biasm (fp16, frag-permuted) ============
__global__ __launch_bounds__(256) void k_prep(
        const float* __restrict__ x, const float* __restrict__ wq, const float* __restrict__ wk,
        const float* __restrict__ wv, const float* __restrict__ bv, const float* __restrict__ wo,
        const float* __restrict__ bias, const int* __restrict__ mask,
        unsigned short* __restrict__ xb, unsigned short* __restrict__ wqt,
        unsigned short* __restrict__ wkt, float* __restrict__ wv2t, float* __restrict__ bv2,
        unsigned short* __restrict__ biasm) {
    __shared__ float t[32][33];
    int bx = blockIdx.x, tid = threadIdx.x;
    if (bx < 2048) {
        int i = bx * 256 + tid;
        float4 v = ((const float4*)x)[i];
        ushort4 o; o.x = f2bf(v.x); o.y = f2bf(v.y); o.z = f2bf(v.z); o.w = f2bf(v.w);
        ((ushort4*)xb)[i] = o;
    } else if (bx < 4096) {
        int g = bx - 2048; int z = g >> 10; g &= 1023;
        const float* src = z ? wk : wq;
        unsigned short* dst = z ? wkt : wqt;
        int be = (g & 31) * 32, bc = (g >> 5) * 32;
        int tx = tid & 31, ty = tid >> 5;
        #pragma unroll
        for (int yy = 0; yy < 32; yy += 8)
            t[ty + yy][tx] = src[(size_t)(be + ty + yy) * DMOD + bc + tx];
        __syncthreads();
        #pragma unroll
        for (int yy = 0; yy < 32; yy += 8)
            dst[(size_t)(bc + ty + yy) * DMOD + be + tx] = f2bf(t[tx][ty + yy]);
    } else if (bx < 4352) {
        int g = bx - 4096;
        int grp = tid >> 6, l = tid & 63;
        int e = g * 4 + grp;
        float out = 0.f;
        #pragma unroll
        for (int it = 0; it < 16; ++it) {
            float v = wv[(size_t)e * DMOD + it * 64 + l] * wo[it * 64 + l];
            #pragma unroll
            for (int off = 1; off < 64; off <<= 1) v += __shfl_xor(v, off, 64);
            if (l == it) out = v;
        }
        if (l < 16) wv2t[l * DMOD + e] = out;
        if (g == 0 && grp == 0) {
            float ob = 0.f;
            #pragma unroll
            for (int it = 0; it < 16; ++it) {
                float v = bv[it * 64 + l] * wo[it * 64 + l];
                #pragma unroll
                for (int off = 1; off < 64; off <<= 1) v += __shfl_xor(v, off, 64);
                if (l == it) ob = v;
            }
            if (l < 16) bv2[l] = ob;
        }
    } else {
        int g = bx - 4352;
        int ti = g & 31, h = (g >> 5) & 15, b = g >> 9;
        int l = tid & 63, pb = tid >> 6;
        int quad = l >> 4, col = l & 15;
        const float* brow = bias + (size_t)(b * 16 + h) * NSEQ * NSEQ;
        const int* mrow = mask + (size_t)b * NSEQ * NSEQ;
        #pragma unroll
        for (int pass = 0; pass < 8; ++pass) {
            int tj = pass * 4 + pb;
            int j = tj * 16 + col;
            ushort4 o;
            #pragma unroll
            for (int rr = 0; rr < 4; ++rr) {
                int i = ti * 16 + quad * 4 + rr;
                float bvv = brow[(size_t)i * NSEQ + j];
                int mk = mrow[(size_t)i * NSEQ + j];
                float val = mk ? bvv : -1.0e4f;
                ((unsigned short*)&o)[rr] = __half_as_ushort(__float2half(val));
            }
            size_t tile = ((size_t)((b * 16 + h) * 32 + ti)) * 32 + tj;
            *(ushort4*)(biasm + tile * 256 + l * 4) = o;
        }
    }
}

// ============ B: mid — u projection + Q/K MFMA GEMM with LDS staging ============
// grid 1536 x 256 thr: [0,512)=k_u ; [512,1536)=gemm.
// gemm: tile 64(m)x64(n), BK=128, LDS 32 KB single-buffered, global_load_lds w=16,
// XOR-swizzled LDS layout (row r, 16B-block c stored at c^(r&7)) -> conflict-free reads.
__global__ __launch_bounds__(256) void k_mid(
        const float* __restrict__ x, const float* __restrict__ wv2t, const float* __restrict__ bv2,
        const unsigned short* __restrict__ xb, const unsigned short* __restrict__ wqt,
        const unsigned short* __restrict__ wkt, const float* __restrict__ bq,
        const float* __restrict__ bk, float* __restrict__ u,
        unsigned short* __restrict__ qT, unsigned short* __restrict__ kT) {
    __shared__ unsigned short lA[64 * 128];   // 16 KB, row stride 128 els (256 B)
    __shared__ unsigned short lB[64 * 128];   // 16 KB
    int bx = blockIdx.x, tid = threadIdx.x;
    if (bx < 512) {
        int wave = bx * 4 + (tid >> 6);
        int l = tid & 63;
        int b = wave >> 9, j = wave & 511;
        const float* xr = x + (size_t)(b * NSEQ + j) * DMOD;
        float p[16];
        #pragma unroll
        for (int h = 0; h < 16; ++h) p[h] = 0.f;
        for (int it = 0; it < 16; ++it) {
            int e = l + it * 64;
            float xv = xr[e];
            #pragma unroll
            for (int h = 0; h < 16; ++h) p[h] += xv * wv2t[h * DMOD + e];
        }
        #pragma unroll
        for (int h = 0; h < 16; ++h) {
            #pragma unroll
            for (int off = 1; off < 64; off <<= 1) p[h] += __shfl_xor(p[h], off, 64);
        }
        float out = 0.f;
        #pragma unroll
        for (int h = 0; h < 16; ++h) if (l == h) out = p[h] + bv2[h];
        if (l < 16) u[(b * 16 + l) * NSEQ + j] = out;
        return;
    }
    int g = bx - 512;
    int z = g >> 9;
    const unsigned short* Wt = z ? wkt : wqt;
    const float* bias = z ? bk : bq;
    unsigned short* outT = z ? kT : qT;
    float scale = z ? 1.f : 0.125f;   // fold /sqrt(HD)=1/8 into q
    int w = tid >> 6, lane = tid & 63;
    int quad = lane >> 4, col = lane & 15;
    int m0 = (g & 31) * 64;
    int n0 = ((g >> 5) & 15) * 64;

    f32x4 acc[4];
    #pragma unroll
    for (int nt = 0; nt < 4; ++nt) acc[nt] = (f32x4){0.f, 0.f, 0.f, 0.f};

    int rl_base = lane >> 4;   // 0..3
    int cs = lane & 15;
    int asw = cs & 7;

    for (int kc = 0; kc < 8; ++kc) {
        int k0 = kc * 128;
        // stage: wave w loads rows w*16..w*16+15 of A and B (4 rows / inst)
        #pragma unroll
        for (int t = 0; t < 4; ++t) {
            int rl = t * 4 + rl_base;          // 0..15
            int row = w * 16 + rl;
            int cg = cs ^ (rl & 7);            // swizzle via global address
            gload_lds16(xb + (size_t)(m0 + row) * DMOD + k0 + cg * 8,
                        &lA[(w * 16 + t * 4) * 128]);
            gload_lds16(Wt + (size_t)(n0 + row) * DMOD + k0 + cg * 8,
                        &lB[(w * 16 + t * 4) * 128]);
        }
        __syncthreads();
        int arow = w * 16 + cs;
        #pragma unroll
        for (int ks = 0; ks < 4; ++ks) {
            int blk = (ks * 4 + quad) ^ asw;
            bf16x8 af = *(const bf16x8*)&lA[arow * 128 + blk * 8];
            #pragma unroll
            for (int nt = 0; nt < 4; ++nt) {
                bf16x8 bfr = *(const bf16x8*)&lB[(nt * 16 + cs) * 128 + blk * 8];
                acc[nt] = __builtin_amdgcn_mfma_f32_16x16x32_bf16(af, bfr, acc[nt], 0, 0, 0);
            }
        }
        __syncthreads();
    }
    #pragma unroll
    for (int nt = 0; nt < 4; ++nt) {
        int n = n0 + nt * 16 + col;
        int h = n >> 6, d = n & 63;
        float bvv = bias[n];
        #pragma unroll
        for (int r = 0; r < 4; ++r) {
            int mg = m0 + w * 16 + quad * 4 + r;
            int b = mg >> 9, i = mg & 511;
            outT[(size_t)((b * 16 + h) * NSEQ + i) * HD + d] = f2bf((acc[nt][r] + bvv) * scale);
        }
    }
}

// ============ C: logits+exp, eW via LDS transpose ============
__global__ __launch_bounds__(256) void k_logits(
        const unsigned short* __restrict__ qT, const unsigned short* __restrict__ kT,
        const unsigned short* __restrict__ biasm,
        unsigned short* __restrict__ eW, float* __restrict__ spart) {
    __shared__ unsigned short elds[4][16][66];
    int tid = threadIdx.x, w = tid >> 6, lane = tid & 63;
    int quad = lane >> 4, col = lane & 15;
    int bx = blockIdx.x;
    int it = bx & 7, jc = (bx >> 3) & 7, h = (bx >> 6) & 15, b = bx >> 10;
    int bh = b * 16 + h;
    int i0 = it * 64 + w * 16;
    int j0 = jc * 64;

    const unsigned short* qbase = qT + ((size_t)(bh * NSEQ + i0 + col)) * HD + quad * 8;
    bf16x8 a0 = *(const bf16x8*)qbase;
    bf16x8 a1 = *(const bf16x8*)(qbase + 32);

    bf16x8 kf0[4], kf1[4];
    uint2 bm[4];
    #pragma unroll
    for (int jt = 0; jt < 4; ++jt) {
        const unsigned short* kbase = kT + ((size_t)(bh * NSEQ + j0 + jt * 16 + col)) * HD + quad * 8;
        kf0[jt] = *(const bf16x8*)kbase;
        kf1[jt] = *(const bf16x8*)(kbase + 32);
        size_t tile = ((size_t)(bh * 32 + it * 4 + w)) * 32 + (jc * 4 + jt);
        bm[jt] = *(const uint2*)(biasm + tile * 256 + lane * 4);
    }

    float sp[4] = {0.f, 0.f, 0.f, 0.f};
    #pragma unroll
    for (int jt = 0; jt < 4; ++jt) {
        f32x4 acc = (f32x4){0.f, 0.f, 0.f, 0.f};
        acc = __builtin_amdgcn_mfma_f32_16x16x32_bf16(a0, kf0[jt], acc, 0, 0, 0);
        acc = __builtin_amdgcn_mfma_f32_16x16x32_bf16(a1, kf1[jt], acc, 0, 0, 0);
        unsigned short hb[4];
        hb[0] = (unsigned short)(bm[jt].x & 0xffffu);
        hb[1] = (unsigned short)(bm[jt].x >> 16);
        hb[2] = (unsigned short)(bm[jt].y & 0xffffu);
        hb[3] = (unsigned short)(bm[jt].y >> 16);
        #pragma unroll
        for (int rr = 0; rr < 4; ++rr) {
            float lg = acc[rr] + __half2float(__ushort_as_half(hb[rr]));
            float ev = __expf(lg);
            sp[rr] += ev;
            elds[w][quad * 4 + rr][jt * 16 + col] = f2bf(ev);
        }
    }
    #pragma unroll
    for (int rr = 0; rr < 4; ++rr) {
        #pragma unroll
        for (int off = 1; off < 16; off <<= 1) sp[rr] += __shfl_xor(sp[rr], off, 64);
    }
    if (col == 0) {
        #pragma unroll
        for (int rr = 0; rr < 4; ++rr)
            spart[((size_t)(bh * NSEQ) + i0 + quad * 4 + rr) * 8 + jc] = sp[rr];
    }
    __syncthreads();
    #pragma unroll
    for (int k2 = 0; k2 < 8; ++k2) {
        int row = (lane >> 5) + k2 * 2;
        int jseg = (lane & 31) * 2;
        uint32_t val = *(const uint32_t*)&elds[w][row][jseg];
        int i = i0 + row;
        *(uint32_t*)(eW + (((size_t)(b * NSEQ + i) * NH + h) * NSEQ) + j0 + jseg) = val;
    }
}

// ============ E: sinv + combine ============
__global__ __launch_bounds__(256) void k_combine(
        const unsigned short* __restrict__ eW, const float* __restrict__ spart,
        const float* __restrict__ u, const float* __restrict__ r,
        const float* __restrict__ bo, float* __restrict__ out) {
    __shared__ __align__(16) unsigned short elds[2][NH][NSEQ];   // 32 KB
    __shared__ float su[2][16];
    __shared__ float red[2][2][3];
    int tid = threadIdx.x, bx = blockIdx.x;
    int ip = bx & 255, b = bx >> 8;
    int i0 = ip * 2;
    const unsigned short* esrc = eW + (size_t)(b * NSEQ + i0) * NH * NSEQ;
    #pragma unroll
    for (int t = 0; t < 8; ++t)
        ((int4*)&elds[0][0][0])[tid + t * 256] = ((const int4*)esrc)[tid + t * 256];
    {
        int il = tid >> 7, hq = (tid >> 3) & 15, jcq = tid & 7;
        float v = spart[((size_t)((b * 16 + hq) * NSEQ) + i0 + il) * 8 + jcq];
        v += __shfl_xor(v, 1, 64); v += __shfl_xor(v, 2, 64); v += __shfl_xor(v, 4, 64);
        if (jcq == 0) su[il][hq] = (v > 0.f) ? 1.f / v : 0.f;
    }
    __syncthreads();
    int il = tid >> 7, jj = tid & 127, j = jj * 4;
    int i = i0 + il;
    float s0 = 0.f, s1 = 0.f, s2 = 0.f, s3 = 0.f;
    #pragma unroll
    for (int h = 0; h < 16; ++h) {
        float wgt = su[il][h];
        float4 uv = *(const float4*)(u + (size_t)(b * 16 + h) * NSEQ + j);
        uint2 ep = *(const uint2*)&elds[il][h][j];
        s0 += bf2f((unsigned short)(ep.x & 0xffffu)) * wgt * uv.x;
        s1 += bf2f((unsigned short)(ep.x >> 16)) * wgt * uv.y;
        s2 += bf2f((unsigned short)(ep.y & 0xffffu)) * wgt * uv.z;
        s3 += bf2f((unsigned short)(ep.y >> 16)) * wgt * uv.w;
    }
    float acc[3];
    #pragma unroll
    for (int c = 0; c < 3; ++c) {
        float4 rv = *(const float4*)(r + ((size_t)(b * 3 + c) * NSEQ + i) * NSEQ + j);
        acc[c] = rv.x * s0 + rv.y * s1 + rv.z * s2 + rv.w * s3;
    }
    #pragma unroll
    for (int c = 0; c < 3; ++c) {
        #pragma unroll
        for (int off = 1; off < 64; off <<= 1) acc[c] += __shfl_xor(acc[c], off, 64);
    }
    int wv = tid >> 6, lane = tid & 63;
    if (lane == 0) {
        red[wv >> 1][wv & 1][0] = acc[0];
        red[wv >> 1][wv & 1][1] = acc[1];
        red[wv >> 1][wv & 1][2] = acc[2];
    }
    __syncthreads();
    if (tid < 6) {
        int ilo = tid / 3, c = tid % 3;
        out[(size_t)(b * NSEQ + i0 + ilo) * 3 + c] = red[ilo][0][c] + red[ilo][1][c] + bo[0];
    }
}

extern "C" void kernel_launch(void* const* d_in, const int* in_sizes, int n_in,
                              void* d_out, int out_size, void* d_ws, size_t ws_size,
                              hipStream_t stream) {
    const float* x    = (const float*)d_in[0];
    const float* rr   = (const float*)d_in[1];
    const float* bias = (const float*)d_in[2];
    const int*   mask = (const int*)d_in[3];
    const float* wq   = (const float*)d_in[4];
    const float* bq   = (const float*)d_in[5];
    const float* wk   = (const float*)d_in[6];
    const float* bk   = (const float*)d_in[7];
    const float* wv   = (const float*)d_in[8];
    const float* bv   = (const float*)d_in[9];
    const float* wo   = (const float*)d_in[10];
    const float* bo   = (const float*)d_in[11];
    float* out = (float*)d_out;

    char* ws = (char*)d_ws;
    unsigned short* xb   = (unsigned short*)(ws + 0);          //  4 MiB
    unsigned short* wqt  = (unsigned short*)(ws + 4194304);    //  2 MiB
    unsigned short* wkt  = (unsigned short*)(ws + 6291456);    //  2 MiB
    float*          wv2t = (float*)(ws + 8388608);             //  64 KiB
    float*          bv2  = (float*)(ws + 8454144);             //  256 B
    float*          u    = (float*)(ws + 8454400);             //  128 KiB
    unsigned short* qT   = (unsigned short*)(ws + 8585472);    //  4 MiB
    unsigned short* kT   = (unsigned short*)(ws + 12779776);   //  4 MiB
    unsigned short* bm   = (unsigned short*)(ws + 16974080);   //  32 MiB fp16, frag-permuted
    unsigned short* eW   = (unsigned short*)(ws + 50528512);   //  32 MiB bf16 [b][i][h][j]
    float*          spart= (float*)(ws + 84082944);            //  1 MiB
    // total ~85.1 MB

    k_prep<<<6400, 256, 0, stream>>>(x, wq, wk, wv, bv, wo, bias, mask,
                                     xb, wqt, wkt, wv2t, bv2, bm);
    k_mid<<<1536, 256, 0, stream>>>(x, wv2t, bv2, xb, wqt, wkt, bq, bk, u, qT, kT);
    k_logits<<<4096, 256, 0, stream>>>(qT, kT, bm, eW, spart);
    k_combine<<<1024, 256, 0, stream>>>(eW, spart, u, rr, bo, out);
}